// Round 11
// baseline (164.141 us; speedup 1.0000x reference)
//
#include <hip/hip_runtime.h>

#define T_DIM 8192
#define N_DIM 8
#define C_DIM 64
#define KB    2048
#define NT    (N_DIM * T_DIM)        // 65536 rows
#define TOTX  ((size_t)NT * C_DIM)   // 4194304 elements
#define LISTCAP 8192
#define TAU   1e-3f
#define MBLK  256                    // merge blocks

// Scratch inside out's x_d region (out + NT), overwritten LAST by xd_kernel.
// Offsets in FLOAT units from out+NT:
#define SCR_COUNT 0                   // int
#define SCR_LIST  16                  // int[8192]            -> ends 8208
#define SCR_PART  8448                // float[256][8]        -> ends 10496
#define SCR_KNS   16384               // float[2048]          -> ends 18432
#define SCR_K     32768               // f16x8[16][2048] (512 KB) -> ends 163840
#define SCR_ROW   262144              // float[65536][8] (2 MB)   -> ends 786432

typedef _Float16 half_t;
typedef _Float16 f16x8 __attribute__((ext_vector_type(8)));
typedef float    f32x16 __attribute__((ext_vector_type(16)));

#define WAITL0() asm volatile("s_waitcnt lgkmcnt(0)" ::: "memory")
#define BAR()    __builtin_amdgcn_s_barrier()

// numpy pairwise sum (n=64) of squares for the np-exact fixup.
__device__ __forceinline__ float np_sumsq64(const float* __restrict__ a) {
    float r[8];
    #pragma unroll
    for (int j = 0; j < 8; ++j) r[j] = __fmul_rn(a[j], a[j]);
    #pragma unroll
    for (int i = 8; i < 64; i += 8)
        #pragma unroll
        for (int j = 0; j < 8; ++j)
            r[j] = __fadd_rn(r[j], __fmul_rn(a[i + j], a[i + j]));
    return __fadd_rn(__fadd_rn(__fadd_rn(r[0], r[1]), __fadd_rn(r[2], r[3])),
                     __fadd_rn(__fadd_rn(r[4], r[5]), __fadd_rn(r[6], r[7])));
}

// ------------------------------------------------------------------ k prep ----
// kscr[ch][part hi/lo][slot][bin] ; hi = -2*k_hi, lo = -4096*(k-k_hi). ||k||^2.
__global__ __launch_bounds__(256) void kprep_kernel(const float* __restrict__ k,
                                                    float* __restrict__ out) {
    float* base = out + NT;
    const int bin = blockIdx.x * 256 + threadIdx.x;   // grid 8 -> 2048
    if (bin == 0) ((int*)base)[SCR_COUNT] = 0;

    float kv[64];
    #pragma unroll
    for (int i = 0; i < 16; ++i)
        *(float4*)&kv[i * 4] = *(const float4*)(k + (size_t)bin * 64 + i * 4);

    float kn = 0.f;
    #pragma unroll
    for (int c = 0; c < 64; ++c) kn = fmaf(kv[c], kv[c], kn);
    base[SCR_KNS + bin] = kn;

    f16x8* kscr = (f16x8*)(base + SCR_K);
    const int ch = bin >> 7, b127 = bin & 127;
    #pragma unroll
    for (int slot = 0; slot < 8; ++slot) {
        f16x8 h8, l8;
        #pragma unroll
        for (int e = 0; e < 8; ++e) {
            float xv = kv[slot * 8 + e];
            half_t hh = (half_t)xv;
            h8[e] = (half_t)(-2.f * (float)hh);
            l8[e] = (half_t)(-4096.f * (xv - (float)hh));
        }
        kscr[(size_t)ch * 2048 + slot * 128 + b127]        = h8;
        kscr[(size_t)ch * 2048 + 1024 + slot * 128 + b127] = l8;
    }
}

// ------------------------------------------------------------------ argmin ----
// Grid 1024: hb = blk&1 (bin half of 1024), rows = (blk>>1)*128. 4 waves.
// LDS-shared k (64-bin chunks, double-buffered), reg-staged. Results per
// (row, hb) go to SCR_ROW; merge_kernel combines halves.
__global__ __launch_bounds__(256, 3) void argmin_kernel(const float* __restrict__ x,
                                                        float* __restrict__ out) {
    __shared__ __align__(16) char smem[35840];
    // [0,16384): buf0 / xhi_s   [16384,32768): buf1 / xlo_s
    // [32768,34816): sxp float[2][128], sxxp float[2][128]

    float* base = out + NT;
    const int tid = threadIdx.x;
    const int l   = tid & 63, w = tid >> 6;
    const int col = l & 31, kg = l >> 5;
    const int hb  = blockIdx.x & 1;
    const int r0  = (blockIdx.x >> 1) * 128;
    const int n   = r0 >> 13;
    const int t0  = r0 & (T_DIM - 1);

    f16x8* xhi_s = (f16x8*)(smem);             // [8 slots][128 rows]
    f16x8* xlo_s = (f16x8*)(smem + 16384);
    float* sxp   = (float*)(smem + 32768);     // [2][128]
    float* sxxp  = (float*)(smem + 33792);     // [2][128]

    // fused x load + f16 hi/lo split (thread: row = tid&127, c-half = tid>>7)
    {
        const int row = tid & 127, chalf = tid >> 7;
        float xv[32];
        #pragma unroll
        for (int j = 0; j < 32; ++j)
            xv[j] = x[((size_t)n * C_DIM + chalf * 32 + j) * T_DIM + t0 + row];
        float sx = 0.f, sxx = 0.f;
        #pragma unroll
        for (int j = 0; j < 32; ++j) { sx += xv[j]; sxx = fmaf(xv[j], xv[j], sxx); }
        sxp[chalf * 128 + row]  = sx;
        sxxp[chalf * 128 + row] = sxx;
        #pragma unroll
        for (int j4 = 0; j4 < 4; ++j4) {
            f16x8 h8, l8;
            #pragma unroll
            for (int e = 0; e < 8; ++e) {
                float v = xv[j4 * 8 + e];
                half_t hh = (half_t)v;
                h8[e] = hh;
                l8[e] = (half_t)(2048.f * (v - (float)hh));
            }
            const int slot = chalf * 4 + j4;
            xhi_s[slot * 128 + row] = h8;
            xlo_s[slot * 128 + row] = l8;
        }
    }
    WAITL0(); BAR();

    // A fragments (persistent registers)
    const int arow = w * 32 + col;
    f16x8 a_hi[4], a_lo[4];
    #pragma unroll
    for (int s = 0; s < 4; ++s) {
        a_hi[s] = xhi_s[(2 * s + kg) * 128 + arow];
        a_lo[s] = xlo_s[(2 * s + kg) * 128 + arow];
    }
    WAITL0(); BAR();    // bufs free for k staging

    const f16x8* kscr = (const f16x8*)(base + SCR_K);
    const int t6 = tid >> 6, t63 = tid & 63;
    f16x8 rk[4];
    auto kload = [&](int ch) {
        const int b0 = hb * 1024 + ch * 64;
        const int CH = b0 >> 7, half = ch & 1;
        const f16x8* src = kscr + (size_t)CH * 2048 + half * 64 + t63;
        #pragma unroll
        for (int i = 0; i < 4; ++i)
            rk[i] = src[(i >> 1) * 1024 + ((i & 1) * 4 + t6) * 128];
    };
    auto kwrite = [&](int bufoff) {
        f16x8* dst = (f16x8*)(smem + bufoff);
        #pragma unroll
        for (int i = 0; i < 4; ++i) dst[i * 256 + tid] = rk[i];
    };

    float bestv[16], best2v[16];
    int   bestb[16];
    #pragma unroll
    for (int r = 0; r < 16; ++r) {
        bestv[r] = __builtin_inff(); best2v[r] = __builtin_inff(); bestb[r] = 0;
    }

    auto compute = [&](int ch, int bufoff) {
        const f16x8* bhi = (const f16x8*)(smem + bufoff);
        const f16x8* blo = bhi + 512;
        #pragma unroll
        for (int t4 = 0; t4 < 2; ++t4) {
            const int lrow = t4 * 32 + col;
            const int binf = hb * 1024 + ch * 64 + lrow;
            const float kn = base[SCR_KNS + binf];
            f16x8 b_hi[4], b_lo[4];
            #pragma unroll
            for (int s = 0; s < 4; ++s) {
                b_hi[s] = bhi[(2 * s + kg) * 64 + lrow];
                b_lo[s] = blo[(2 * s + kg) * 64 + lrow];
            }
            f32x16 acc1, acc2;
            #pragma unroll
            for (int r = 0; r < 16; ++r) { acc1[r] = kn; acc2[r] = 0.f; }
            #pragma unroll
            for (int s = 0; s < 4; ++s) {
                acc1 = __builtin_amdgcn_mfma_f32_32x32x16_f16(a_hi[s], b_hi[s], acc1, 0, 0, 0);
                acc2 = __builtin_amdgcn_mfma_f32_32x32x16_f16(a_hi[s], b_lo[s], acc2, 0, 0, 0);
                acc2 = __builtin_amdgcn_mfma_f32_32x32x16_f16(a_lo[s], b_hi[s], acc2, 0, 0, 0);
            }
            #pragma unroll
            for (int r = 0; r < 16; ++r) {
                float sv = fmaf(acc2[r], 4.8828125e-4f, acc1[r]);  // kn - 2*dot
                best2v[r] = fminf(best2v[r], fmaxf(sv, bestv[r]));
                if (sv < bestv[r]) { bestv[r] = sv; bestb[r] = binf; }
            }
        }
    };

    // pipeline: 16 chunks of 64 bins
    kload(0);
    kwrite(0);
    kload(1);
    WAITL0(); BAR();
    #pragma unroll 1
    for (int ch = 0; ch < 16; ++ch) {
        const int cur = (ch & 1) ? 16384 : 0;
        const int nxt = (ch & 1) ? 0 : 16384;
        if (ch < 15) {
            kwrite(nxt);               // vmcnt wait auto-inserted for rk
            if (ch < 14) kload(ch + 2);
        }
        compute(ch, cur);
        WAITL0(); BAR();
    }

    // merge across the 32 column-lanes of each half, tracking 2nd-best
    #pragma unroll
    for (int off = 1; off <= 16; off <<= 1) {
        #pragma unroll
        for (int r = 0; r < 16; ++r) {
            float ov = __shfl_xor(bestv[r], off, 64);
            int   ob = __shfl_xor(bestb[r], off, 64);
            float o2 = __shfl_xor(best2v[r], off, 64);
            float mx = fmaxf(bestv[r], ov);
            best2v[r] = fminf(fminf(best2v[r], o2), mx);
            if (ov < bestv[r] || (ov == bestv[r] && ob < bestb[r])) {
                bestv[r] = ov; bestb[r] = ob;
            }
        }
    }

    // write per-(row, hb) results to SCR_ROW (lanes col==0: 16 rows each)
    if (col == 0) {
        float* rr = base + SCR_ROW;
        #pragma unroll
        for (int r = 0; r < 16; ++r) {
            const int row_loc = w * 32 + 4 * kg + (r & 3) + 8 * (r >> 2);
            const int grow = r0 + row_loc;
            float* p = rr + (size_t)grow * 8 + hb * 3;
            p[0] = bestv[r];
            p[1] = best2v[r];
            p[2] = __int_as_float(bestb[r]);
            if (hb == 0) {
                rr[(size_t)grow * 8 + 6] = sxp[row_loc] + sxp[128 + row_loc];
                rr[(size_t)grow * 8 + 7] = sxxp[row_loc] + sxxp[128 + row_loc];
            }
        }
    }
}

// ------------------------------------------------------------------ merge ----
// One thread per row: combine the two bin-halves, flag near-ties, write x_l,
// accumulate block partial sums.
__global__ __launch_bounds__(256) void merge_kernel(const float* __restrict__ mask,
                                                    float* __restrict__ out) {
    float* base = out + NT;
    const int tid = threadIdx.x;
    const int row = blockIdx.x * 256 + tid;
    const float* rr = base + SCR_ROW + (size_t)row * 8;

    float v0 = rr[0], b20 = rr[1];
    int   i0 = __float_as_int(rr[2]);
    float v1 = rr[3], b21 = rr[4];
    int   i1 = __float_as_int(rr[5]);
    float sx = rr[6], sxx = rr[7];

    float bv = v0; int bb = i0;
    if (v1 < v0) { bv = v1; bb = i1; }      // tie -> half 0 (lower bins)
    float b2 = fminf(fminf(b20, b21), fmaxf(v0, v1));

    if (b2 - bv < TAU) {
        int idx = atomicAdd((int*)base + SCR_COUNT, 1);
        if (idx < LISTCAP) ((int*)base + SCR_LIST)[idx] = row;
    }
    out[row] = (float)bb;

    const float m  = mask[row];
    const float d2 = sxx + bv;
    float vals[5] = { m * d2, d2, m, sx, sxx };

    #pragma unroll
    for (int off = 1; off <= 32; off <<= 1)
        #pragma unroll
        for (int q = 0; q < 5; ++q) vals[q] += __shfl_xor(vals[q], off, 64);
    __shared__ float sacc[4][8];
    const int wid = tid >> 6, lane = tid & 63;
    if (lane == 0)
        #pragma unroll
        for (int q = 0; q < 5; ++q) sacc[wid][q] = vals[q];
    __syncthreads();
    if (tid == 0) {
        float* partials = base + SCR_PART;
        #pragma unroll
        for (int q = 0; q < 5; ++q)
            partials[(size_t)blockIdx.x * 8 + q] =
                sacc[0][q] + sacc[1][q] + sacc[2][q] + sacc[3][q];
    }
}

// ------------------------------------------------------------------ fixup ----
// np-f32-exact recompute of flagged near-tie rows (first-occurrence argmin).
__global__ __launch_bounds__(256) void fixup_kernel(const float* __restrict__ x,
                                                    const float* __restrict__ k,
                                                    float* __restrict__ out) {
    __shared__ float xv[C_DIM];
    __shared__ float sxxs;
    __shared__ float redv[4];
    __shared__ int   redb[4];
    const int tid = threadIdx.x;
    const int* count    = (const int*)(out + NT) + SCR_COUNT;
    const int* flaglist = (const int*)(out + NT) + SCR_LIST;
    int cnt = *count;
    if (cnt > LISTCAP) cnt = LISTCAP;

    for (int it = blockIdx.x; it < cnt; it += gridDim.x) {
        const int row = flaglist[it];
        const int n = row >> 13, t = row & (T_DIM - 1);
        if (tid < C_DIM)
            xv[tid] = x[((size_t)n * C_DIM + tid) * T_DIM + t];
        __syncthreads();
        if (tid == 0) sxxs = np_sumsq64(xv);
        __syncthreads();
        const float xx = sxxs;

        float bv = __builtin_inff();
        int   bb = 0x7fffffff;
        for (int b = tid; b < KB; b += 256) {
            const float* kr = k + (size_t)b * C_DIM;
            float dot = 0.f;
            #pragma unroll
            for (int c = 0; c < C_DIM; ++c)
                dot = fmaf(xv[c], kr[c], dot);
            float kk = np_sumsq64(kr);
            float d  = __fadd_rn(__fsub_rn(xx, __fadd_rn(dot, dot)), kk);
            if (d < bv) { bv = d; bb = b; }
        }
        #pragma unroll
        for (int off = 1; off <= 32; off <<= 1) {
            float ov = __shfl_xor(bv, off, 64);
            int   ob = __shfl_xor(bb, off, 64);
            if (ov < bv || (ov == bv && ob < bb)) { bv = ov; bb = ob; }
        }
        const int wid = tid >> 6, lane = tid & 63;
        if (lane == 0) { redv[wid] = bv; redb[wid] = bb; }
        __syncthreads();
        if (tid == 0) {
            float fv = redv[0]; int fb = redb[0];
            #pragma unroll
            for (int wq = 1; wq < 4; ++wq) {
                if (redv[wq] < fv || (redv[wq] == fv && redb[wq] < fb)) {
                    fv = redv[wq]; fb = redb[wq];
                }
            }
            out[row] = (float)fb;
        }
        __syncthreads();
    }
}

// ------------------------------------------------------------- finalize ----
__global__ __launch_bounds__(256) void finalize_kernel(float* __restrict__ out) {
    const float* partials = (out + NT) + SCR_PART;
    const int tid = threadIdx.x;
    double vals[5] = {0, 0, 0, 0, 0};
    for (int i = tid; i < MBLK; i += 256)
        #pragma unroll
        for (int q = 0; q < 5; ++q) vals[q] += (double)partials[(size_t)i * 8 + q];
    #pragma unroll
    for (int off = 1; off <= 32; off <<= 1)
        #pragma unroll
        for (int q = 0; q < 5; ++q) vals[q] += __shfl_xor(vals[q], off, 64);
    __shared__ double sred[4][5];
    const int wid = tid >> 6, lane = tid & 63;
    if (lane == 0)
        for (int q = 0; q < 5; ++q) sred[wid][q] = vals[q];
    __syncthreads();
    if (tid == 0) {
        double cm  = sred[0][0] + sred[1][0] + sred[2][0] + sred[3][0];
        double fs  = sred[0][1] + sred[1][1] + sred[2][1] + sred[3][1];
        double ms  = sred[0][2] + sred[1][2] + sred[2][2] + sred[3][2];
        double sx  = sred[0][3] + sred[1][3] + sred[2][3] + sred[3][3];
        double sxx = sred[0][4] + sred[1][4] + sred[2][4] + sred[3][4];
        double sz  = (double)TOTX;
        out[NT + TOTX + 0] = (float)(cm / (ms * (double)C_DIM));
        out[NT + TOTX + 1] = (float)(fs / (double)NT);
        out[NT + TOTX + 2] = (float)sqrt(fmax(0.0, (sxx - sx * sx / sz) / sz));
    }
}

// --------------------------------------------------------------------- x_d ----
// Runs LAST: overwrites the scratch region with real x_d values.
__global__ __launch_bounds__(256) void xd_kernel(const float* __restrict__ mask,
                                                 const float* __restrict__ k,
                                                 float* __restrict__ out) {
    const int row = blockIdx.x * 256 + threadIdx.x;
    const int n = row >> 13, t = row & (T_DIM - 1);
    const int b = (int)out[row];
    const float m = mask[row];
    const float* kr = k + (size_t)b * C_DIM;
    float* xd = out + NT;
    #pragma unroll
    for (int c = 0; c < C_DIM; ++c)
        xd[((size_t)n * C_DIM + c) * T_DIM + t] = kr[c] * m;
}

// ----------------------------------------------------------------- launch ----
extern "C" void kernel_launch(void* const* d_in, const int* in_sizes, int n_in,
                              void* d_out, int out_size, void* d_ws, size_t ws_size,
                              hipStream_t stream) {
    (void)in_sizes; (void)n_in; (void)out_size; (void)d_ws; (void)ws_size;
    const float* x    = (const float*)d_in[0];
    const float* mask = (const float*)d_in[1];
    const float* k    = (const float*)d_in[2];
    float* out = (float*)d_out;

    kprep_kernel<<<KB / 256, 256, 0, stream>>>(k, out);
    argmin_kernel<<<1024, 256, 0, stream>>>(x, out);
    merge_kernel<<<MBLK, 256, 0, stream>>>(mask, out);
    fixup_kernel<<<64, 256, 0, stream>>>(x, k, out);
    finalize_kernel<<<1, 256, 0, stream>>>(out);
    xd_kernel<<<NT / 256, 256, 0, stream>>>(mask, k, out);
}